// Round 2
// baseline (1614.527 us; speedup 1.0000x reference)
//
#include <hip/hip_runtime.h>
#include <hip/hip_bf16.h>
#include <math.h>

// FAGCN: N=50000 nodes, E=800000 edges, H=128, OUT=16, L=2
// Inputs: x[N,128] f32, edge_index[2,E] int32 (harness casts integer->int),
//         W_in[128,128], b_in[128], Wg[L,256], bg[L], W_out[128,16], b_out[16]
// Output: log_softmax(h @ W_out + b_out)  [N,16] f32

#define EPS_RES 0.3f
constexpr int HD = 128;   // hidden dim
constexpr int OD = 16;    // output dim

// ---- degree count (float atomic of 1.0; exact for small counts) ----
__global__ void k_deg(const int* __restrict__ row, float* __restrict__ dn, int E) {
    int e = blockIdx.x * blockDim.x + threadIdx.x;
    if (e < E) unsafeAtomicAdd(&dn[row[e]], 1.0f);
}

__global__ void k_dn(float* __restrict__ dn, int N) {
    int v = blockIdx.x * blockDim.x + threadIdx.x;
    if (v < N) {
        float d = dn[v];
        d = d < 1.0f ? 1.0f : d;
        dn[v] = rsqrtf(d);
    }
}

// ---- h = relu(x @ W_in + b_in); also writes raw = h ----
__global__ __launch_bounds__(256) void k_gemm_in(
        const float* __restrict__ x, const float* __restrict__ W,
        const float* __restrict__ bias,
        float* __restrict__ h, float* __restrict__ raw, int N) {
    __shared__ float Ws[HD * HD];   // 64 KB
    __shared__ float xs[2 * HD];
    int t = threadIdx.x;
    for (int i = t; i < HD * HD; i += 256) Ws[i] = W[i];
    int col = t & 127;
    int rl  = t >> 7;            // 0 or 1: which of the 2 rows this thread handles
    float bv = bias[col];
    for (int r0 = blockIdx.x * 2; r0 < N; r0 += gridDim.x * 2) {
        __syncthreads();                       // protect xs (and first-iter Ws)
        int rr = r0 + (t >> 7);
        if (rr < N) xs[t] = x[rr * HD + (t & 127)];
        __syncthreads();
        int r = r0 + rl;
        if (r < N) {
            float acc = bv;
            const float* xrow = &xs[rl * HD];
            #pragma unroll 8
            for (int k = 0; k < HD; ++k) acc += xrow[k] * Ws[k * HD + col];
            float val = acc > 0.0f ? acc : 0.0f;
            h[r * HD + col]   = val;
            raw[r * HD + col] = val;
        }
    }
}

// ---- per-node gate projections: a[v] = h[v]·Wg1, b[v] = h[v]·Wg2 ----
// one wave per node; lane l holds float2 of the row
__global__ __launch_bounds__(256) void k_ab(
        const float* __restrict__ h, const float* __restrict__ Wg /* 256 floats */,
        float* __restrict__ a, float* __restrict__ b, int N) {
    int wid  = (int)((blockIdx.x * (size_t)blockDim.x + threadIdx.x) >> 6);
    int lane = threadIdx.x & 63;
    if (wid >= N) return;
    float2 hv = *(const float2*)(&h[wid * HD + lane * 2]);
    float2 w1 = *(const float2*)(&Wg[lane * 2]);
    float2 w2 = *(const float2*)(&Wg[HD + lane * 2]);
    float pa = hv.x * w1.x + hv.y * w1.y;
    float pb = hv.x * w2.x + hv.y * w2.y;
    #pragma unroll
    for (int m = 32; m; m >>= 1) {
        pa += __shfl_xor(pa, m);
        pb += __shfl_xor(pb, m);
    }
    if (lane == 0) { a[wid] = pa; b[wid] = pb; }
}

// ---- per-edge scalar: norm[e] = tanh(a[r]+b[c]+bg) * dn[r]*dn[c] ----
__global__ void k_norm(const int* __restrict__ row, const int* __restrict__ col,
                       const float* __restrict__ a, const float* __restrict__ b,
                       const float* __restrict__ dn, const float* __restrict__ bg,
                       int layer, float* __restrict__ norm, int E) {
    int e = blockIdx.x * blockDim.x + threadIdx.x;
    if (e >= E) return;
    int r = row[e], c = col[e];
    float g = tanhf(a[r] + b[c] + bg[layer]);
    norm[e] = g * dn[r] * dn[c];
}

// ---- scatter: agg[col[e]] += norm[e] * h[row[e]] ; one wave per edge ----
__global__ __launch_bounds__(256) void k_scatter(
        const int* __restrict__ row, const int* __restrict__ col,
        const float* __restrict__ norm, const float* __restrict__ h,
        float* __restrict__ agg, int E) {
    int e = (int)((blockIdx.x * (size_t)blockDim.x + threadIdx.x) >> 6);
    if (e >= E) return;
    int lane = threadIdx.x & 63;
    int r = row[e], c = col[e];
    float nv = norm[e];
    float2 hv = *(const float2*)(&h[r * HD + lane * 2]);
    float* dst = &agg[c * HD + lane * 2];
    unsafeAtomicAdd(dst,     nv * hv.x);
    unsafeAtomicAdd(dst + 1, nv * hv.y);
}

// ---- h = EPS*raw + agg (vectorized) ----
__global__ void k_update(const float4* __restrict__ raw, const float4* __restrict__ agg,
                         float4* __restrict__ h, int total4) {
    int i = blockIdx.x * blockDim.x + threadIdx.x;
    if (i < total4) {
        float4 r = raw[i], g = agg[i];
        h[i] = make_float4(EPS_RES * r.x + g.x, EPS_RES * r.y + g.y,
                           EPS_RES * r.z + g.z, EPS_RES * r.w + g.w);
    }
}

// ---- out = log_softmax(h @ W_out + b_out); 16 threads per node ----
__global__ __launch_bounds__(256) void k_out(
        const float* __restrict__ h, const float* __restrict__ W,
        const float* __restrict__ bias, float* __restrict__ out, int N) {
    __shared__ float Ws[HD * OD];   // 8 KB
    __shared__ float hs[16 * HD];   // 8 KB (16 nodes per block)
    int t = threadIdx.x;
    for (int i = t; i < HD * OD; i += 256) Ws[i] = W[i];
    for (int n0 = blockIdx.x * 16; n0 < N; n0 += gridDim.x * 16) {
        __syncthreads();
        for (int i = t; i < 16 * HD; i += 256) {
            int node = n0 + (i >> 7);
            hs[i] = (node < N) ? h[node * HD + (i & 127)] : 0.0f;
        }
        __syncthreads();
        int n = n0 + (t >> 4);
        int j = t & 15;
        if (n < N) {
            const float* hrow = &hs[(t >> 4) * HD];
            float acc = bias[j];
            #pragma unroll 8
            for (int k = 0; k < HD; ++k) acc += hrow[k] * Ws[k * OD + j];
            float m = acc;
            #pragma unroll
            for (int msk = 8; msk; msk >>= 1) m = fmaxf(m, __shfl_xor(m, msk, 16));
            float ex = expf(acc - m);
            float s = ex;
            #pragma unroll
            for (int msk = 8; msk; msk >>= 1) s += __shfl_xor(s, msk, 16);
            out[n * OD + j] = acc - m - logf(s);
        }
    }
}

extern "C" void kernel_launch(void* const* d_in, const int* in_sizes, int n_in,
                              void* d_out, int out_size, void* d_ws, size_t ws_size,
                              hipStream_t stream) {
    const float* x     = (const float*)d_in[0];
    const int*   ei    = (const int*)  d_in[1];
    const float* W_in  = (const float*)d_in[2];
    const float* b_in  = (const float*)d_in[3];
    const float* Wg    = (const float*)d_in[4];
    const float* bg    = (const float*)d_in[5];
    const float* W_out = (const float*)d_in[6];
    const float* b_out = (const float*)d_in[7];
    float* out = (float*)d_out;

    const int N = in_sizes[0] / HD;
    const int E = in_sizes[1] / 2;
    const int L = in_sizes[5];
    const int* row = ei;
    const int* col = ei + E;

    // ---- workspace bump allocator (256B aligned) ----
    char* ws = (char*)d_ws;
    size_t off = 0;
    auto alloc = [&](size_t bytes) -> void* {
        void* p = ws + off;
        off = (off + bytes + 255) & ~(size_t)255;
        return p;
    };
    float* dn   = (float*)alloc((size_t)N * 4);
    float* av   = (float*)alloc((size_t)N * 4);
    float* bv   = (float*)alloc((size_t)N * 4);
    float* nrm  = (float*)alloc((size_t)E * 4);
    float* h    = (float*)alloc((size_t)N * HD * 4);
    float* raw  = (float*)alloc((size_t)N * HD * 4);
    float* agg  = (float*)alloc((size_t)N * HD * 4);
    (void)ws_size;

    // degree -> dn
    hipMemsetAsync(dn, 0, (size_t)N * 4, stream);
    k_deg<<<(E + 255) / 256, 256, 0, stream>>>(row, dn, E);
    k_dn <<<(N + 255) / 256, 256, 0, stream>>>(dn, N);

    // h = relu(x @ W_in + b_in), raw = h
    k_gemm_in<<<512, 256, 0, stream>>>(x, W_in, b_in, h, raw, N);

    const int totalF = N * HD;
    for (int i = 0; i < L; ++i) {
        k_ab<<<(N + 3) / 4, 256, 0, stream>>>(h, Wg + i * 2 * HD, av, bv, N);
        k_norm<<<(E + 255) / 256, 256, 0, stream>>>(row, col, av, bv, dn, bg, i, nrm, E);
        hipMemsetAsync(agg, 0, (size_t)totalF * 4, stream);
        k_scatter<<<(E + 3) / 4, 256, 0, stream>>>(row, col, nrm, h, agg, E);
        k_update<<<(totalF / 4 + 255) / 256, 256, 0, stream>>>(
            (const float4*)raw, (const float4*)agg, (float4*)h, totalF / 4);
    }

    k_out<<<(N + 15) / 16, 256, 0, stream>>>(h, W_out, b_out, out, N);
}

// Round 3
// 522.556 us; speedup vs baseline: 3.0897x; 3.0897x over previous
//
#include <hip/hip_runtime.h>
#include <hip/hip_bf16.h>
#include <math.h>

// FAGCN: N=50000 nodes, E=800000 edges, H=128, OUT=16, L=2
// Round 2 -> 3: replace atomic scatter (800MB fabric writes/layer, 650us) with
// CSR-by-destination + one-wave-per-node gather-aggregate. Gate + norm + residual
// fused into the aggregate kernel.

#define EPS_RES 0.3f
constexpr int HD = 128;   // hidden dim
constexpr int OD = 16;    // output dim

// ---- degree count over ROW (for dn), float atomics ----
__global__ void k_deg(const int* __restrict__ row, float* __restrict__ dn, int E) {
    int e = blockIdx.x * blockDim.x + threadIdx.x;
    if (e < E) unsafeAtomicAdd(&dn[row[e]], 1.0f);
}

__global__ void k_dn(float* __restrict__ dn, int N) {
    int v = blockIdx.x * blockDim.x + threadIdx.x;
    if (v < N) {
        float d = dn[v];
        d = d < 1.0f ? 1.0f : d;
        dn[v] = rsqrtf(d);
    }
}

// ---- CSR build: histogram by col ----
__global__ void k_count(const int* __restrict__ col, int* __restrict__ cnt,
                        int* __restrict__ pos, int E) {
    int e = blockIdx.x * blockDim.x + threadIdx.x;
    if (e < E) pos[e] = atomicAdd(&cnt[col[e]], 1);
}

// single-block exclusive scan of cnt[N] -> rowptr[N+1]
__global__ __launch_bounds__(1024) void k_scan(const int* __restrict__ cnt,
                                               int* __restrict__ rowptr, int N) {
    __shared__ int sums[1024];
    int t = threadIdx.x;
    int C = (N + 1023) / 1024;
    int beg = t * C, end = beg + C; if (end > N) end = N; if (beg > N) beg = N;
    int s = 0;
    for (int i = beg; i < end; ++i) s += cnt[i];
    sums[t] = s;
    __syncthreads();
    for (int d = 1; d < 1024; d <<= 1) {
        int v = (t >= d) ? sums[t - d] : 0;
        __syncthreads();
        sums[t] += v;
        __syncthreads();
    }
    int pre = (t == 0) ? 0 : sums[t - 1];
    for (int i = beg; i < end; ++i) { rowptr[i] = pre; pre += cnt[i]; }
    if (t == 1023) rowptr[N] = pre;
}

// fill slots: erow[rowptr[col[e]] + pos[e]] = row[e]
__global__ void k_fill(const int* __restrict__ row, const int* __restrict__ col,
                       const int* __restrict__ rowptr, const int* __restrict__ pos,
                       int* __restrict__ erow, int E) {
    int e = blockIdx.x * blockDim.x + threadIdx.x;
    if (e < E) erow[rowptr[col[e]] + pos[e]] = row[e];
}

// ---- h = relu(x @ W_in + b_in) -> h0 ----
__global__ __launch_bounds__(256) void k_gemm_in(
        const float* __restrict__ x, const float* __restrict__ W,
        const float* __restrict__ bias, float* __restrict__ h, int N) {
    __shared__ float Ws[HD * HD];   // 64 KB
    __shared__ float xs[2 * HD];
    int t = threadIdx.x;
    for (int i = t; i < HD * HD; i += 256) Ws[i] = W[i];
    int col = t & 127;
    int rl  = t >> 7;
    float bv = bias[col];
    for (int r0 = blockIdx.x * 2; r0 < N; r0 += gridDim.x * 2) {
        __syncthreads();
        int rr = r0 + (t >> 7);
        if (rr < N) xs[t] = x[rr * HD + (t & 127)];
        __syncthreads();
        int r = r0 + rl;
        if (r < N) {
            float acc = bv;
            const float* xrow = &xs[rl * HD];
            #pragma unroll 8
            for (int k = 0; k < HD; ++k) acc += xrow[k] * Ws[k * HD + col];
            h[r * HD + col] = acc > 0.0f ? acc : 0.0f;
        }
    }
}

// ---- per-node gate projections, packed: adn[v]=(h[v]@Wg1, dn[v]), bplus[v]=h[v]@Wg2+bg ----
__global__ __launch_bounds__(256) void k_ab(
        const float* __restrict__ h, const float* __restrict__ Wg /*256 floats*/,
        const float* __restrict__ bg, int layer, const float* __restrict__ dn,
        float2* __restrict__ adn, float* __restrict__ bplus, int N) {
    int wid  = (int)((blockIdx.x * (size_t)blockDim.x + threadIdx.x) >> 6);
    int lane = threadIdx.x & 63;
    if (wid >= N) return;
    float2 hv = *(const float2*)(&h[wid * HD + lane * 2]);
    float2 w1 = *(const float2*)(&Wg[lane * 2]);
    float2 w2 = *(const float2*)(&Wg[HD + lane * 2]);
    float pa = hv.x * w1.x + hv.y * w1.y;
    float pb = hv.x * w2.x + hv.y * w2.y;
    #pragma unroll
    for (int m = 32; m; m >>= 1) {
        pa += __shfl_xor(pa, m);
        pb += __shfl_xor(pb, m);
    }
    if (lane == 0) {
        adn[wid]   = make_float2(pa, dn[wid]);
        bplus[wid] = pb + bg[layer];
    }
}

// ---- aggregate: h_out[v] = EPS*h0[v] + sum_{e: col=v} tanh(a[r]+b[v]+bg)*dn[r]*dn[v]*h_in[r]
// one wave per destination node
__global__ __launch_bounds__(256) void k_agg(
        const int* __restrict__ rowptr, const int* __restrict__ erow,
        const float2* __restrict__ adn, const float* __restrict__ bplus,
        const float* __restrict__ dn,
        const float* __restrict__ h_in, const float* __restrict__ h0,
        float* __restrict__ h_out, int N) {
    int v = (int)((blockIdx.x * (size_t)blockDim.x + threadIdx.x) >> 6);
    if (v >= N) return;
    int lane = threadIdx.x & 63;
    int beg = rowptr[v], end = rowptr[v + 1];
    float bv  = bplus[v];
    float dnv = dn[v];
    float accx = 0.0f, accy = 0.0f;
    for (int s0 = beg; s0 < end; s0 += 64) {
        int m = end - s0; if (m > 64) m = 64;
        int r_l = 0; float nrm_l = 0.0f;
        if (lane < m) {
            r_l = erow[s0 + lane];
            float2 ad = adn[r_l];
            nrm_l = tanhf(ad.x + bv) * ad.y * dnv;
        }
        for (int j = 0; j < m; ++j) {
            int   r  = __shfl(r_l, j);
            float nv = __shfl(nrm_l, j);
            float2 hv = *(const float2*)(&h_in[r * HD + lane * 2]);
            accx += nv * hv.x;
            accy += nv * hv.y;
        }
    }
    float2 rw = *(const float2*)(&h0[v * HD + lane * 2]);
    float2 o = make_float2(EPS_RES * rw.x + accx, EPS_RES * rw.y + accy);
    *(float2*)(&h_out[v * HD + lane * 2]) = o;
}

// ---- out = log_softmax(h @ W_out + b_out); 16 threads per node ----
__global__ __launch_bounds__(256) void k_out(
        const float* __restrict__ h, const float* __restrict__ W,
        const float* __restrict__ bias, float* __restrict__ out, int N) {
    __shared__ float Ws[HD * OD];
    __shared__ float hs[16 * HD];
    int t = threadIdx.x;
    for (int i = t; i < HD * OD; i += 256) Ws[i] = W[i];
    for (int n0 = blockIdx.x * 16; n0 < N; n0 += gridDim.x * 16) {
        __syncthreads();
        for (int i = t; i < 16 * HD; i += 256) {
            int node = n0 + (i >> 7);
            hs[i] = (node < N) ? h[node * HD + (i & 127)] : 0.0f;
        }
        __syncthreads();
        int n = n0 + (t >> 4);
        int j = t & 15;
        if (n < N) {
            const float* hrow = &hs[(t >> 4) * HD];
            float acc = bias[j];
            #pragma unroll 8
            for (int k = 0; k < HD; ++k) acc += hrow[k] * Ws[k * OD + j];
            float m = acc;
            #pragma unroll
            for (int msk = 8; msk; msk >>= 1) m = fmaxf(m, __shfl_xor(m, msk, 16));
            float ex = expf(acc - m);
            float s = ex;
            #pragma unroll
            for (int msk = 8; msk; msk >>= 1) s += __shfl_xor(s, msk, 16);
            out[n * OD + j] = acc - m - logf(s);
        }
    }
}

extern "C" void kernel_launch(void* const* d_in, const int* in_sizes, int n_in,
                              void* d_out, int out_size, void* d_ws, size_t ws_size,
                              hipStream_t stream) {
    const float* x     = (const float*)d_in[0];
    const int*   ei    = (const int*)  d_in[1];
    const float* W_in  = (const float*)d_in[2];
    const float* b_in  = (const float*)d_in[3];
    const float* Wg    = (const float*)d_in[4];
    const float* bg    = (const float*)d_in[5];
    const float* W_out = (const float*)d_in[6];
    const float* b_out = (const float*)d_in[7];
    float* out = (float*)d_out;

    const int N = in_sizes[0] / HD;
    const int E = in_sizes[1] / 2;
    const int L = in_sizes[5];
    const int* row = ei;
    const int* col = ei + E;

    // ---- workspace bump allocator (256B aligned) ----
    char* ws = (char*)d_ws;
    size_t off = 0;
    auto alloc = [&](size_t bytes) -> void* {
        void* p = ws + off;
        off = (off + bytes + 255) & ~(size_t)255;
        return p;
    };
    float*  dn     = (float*) alloc((size_t)N * 4);
    float2* adn    = (float2*)alloc((size_t)N * 8);
    float*  bplus  = (float*) alloc((size_t)N * 4);
    int*    cnt    = (int*)   alloc((size_t)N * 4);
    int*    rowptr = (int*)   alloc(((size_t)N + 1) * 4);
    int*    pos    = (int*)   alloc((size_t)E * 4);
    int*    erow   = (int*)   alloc((size_t)E * 4);
    float*  hbuf0  = (float*) alloc((size_t)N * HD * 4);   // raw (initial h)
    float*  hbuf1  = (float*) alloc((size_t)N * HD * 4);
    float*  hbuf2  = (float*) alloc((size_t)N * HD * 4);
    (void)ws_size;

    // degree (over row) -> dn
    hipMemsetAsync(dn, 0, (size_t)N * 4, stream);
    k_deg<<<(E + 255) / 256, 256, 0, stream>>>(row, dn, E);
    k_dn <<<(N + 255) / 256, 256, 0, stream>>>(dn, N);

    // CSR by destination (col) — layer-independent, built once per launch
    hipMemsetAsync(cnt, 0, (size_t)N * 4, stream);
    k_count<<<(E + 255) / 256, 256, 0, stream>>>(col, cnt, pos, E);
    k_scan <<<1, 1024, 0, stream>>>(cnt, rowptr, N);
    k_fill <<<(E + 255) / 256, 256, 0, stream>>>(row, col, rowptr, pos, erow, E);

    // h0 = relu(x @ W_in + b_in)
    k_gemm_in<<<512, 256, 0, stream>>>(x, W_in, b_in, hbuf0, N);

    float* h_cur = hbuf0;
    float* bufs[2] = { hbuf1, hbuf2 };
    for (int i = 0; i < L; ++i) {
        k_ab<<<(N + 3) / 4, 256, 0, stream>>>(h_cur, Wg + i * 2 * HD, bg, i, dn, adn, bplus, N);
        float* h_next = bufs[i & 1];
        k_agg<<<(N + 3) / 4, 256, 0, stream>>>(rowptr, erow, adn, bplus, dn,
                                               h_cur, hbuf0, h_next, N);
        h_cur = h_next;
    }

    k_out<<<(N + 15) / 16, 256, 0, stream>>>(h_cur, W_out, b_out, out, N);
}

// Round 4
// 425.892 us; speedup vs baseline: 3.7909x; 1.2270x over previous
//
#include <hip/hip_runtime.h>
#include <hip/hip_bf16.h>
#include <math.h>

// FAGCN: N=50000, E=800000, H=128, OUT=16, L=2
// Round 3 -> 4: (1) MFMA bf16 input GEMM (was 100us f32-VALU, MfmaUtil=0),
// (2) h stored bf16 between layers (halves 410MB/layer edge gather),
// (3) gate projections fused into k_agg epilogue (wave holds output row).
// h0 residual kept f32.

#define EPS_RES 0.3f
constexpr int HD = 128;
constexpr int OD = 16;

typedef __attribute__((ext_vector_type(8))) short short8v;   // 8 x bf16 (4 VGPR)
typedef __attribute__((ext_vector_type(4))) float f32x4;

__device__ __forceinline__ unsigned short f2bf(float f) {    // RNE f32->bf16
    unsigned u = __builtin_bit_cast(unsigned, f);
    u += 0x7fffu + ((u >> 16) & 1u);
    return (unsigned short)(u >> 16);
}
__device__ __forceinline__ float bf2f(unsigned s) {
    return __builtin_bit_cast(float, s << 16);
}

// ---- degree over row -> dn = clip(deg,1)^-0.5 ----
__global__ void k_deg(const int* __restrict__ row, float* __restrict__ dn, int E) {
    int e = blockIdx.x * blockDim.x + threadIdx.x;
    if (e < E) unsafeAtomicAdd(&dn[row[e]], 1.0f);
}
__global__ void k_dn(float* __restrict__ dn, int N) {
    int v = blockIdx.x * blockDim.x + threadIdx.x;
    if (v < N) {
        float d = dn[v];
        d = d < 1.0f ? 1.0f : d;
        dn[v] = rsqrtf(d);
    }
}

// ---- CSR build by destination (col) ----
__global__ void k_count(const int* __restrict__ col, int* __restrict__ cnt,
                        int* __restrict__ pos, int E) {
    int e = blockIdx.x * blockDim.x + threadIdx.x;
    if (e < E) pos[e] = atomicAdd(&cnt[col[e]], 1);
}
__global__ __launch_bounds__(1024) void k_scan(const int* __restrict__ cnt,
                                               int* __restrict__ rowptr, int N) {
    __shared__ int sums[1024];
    int t = threadIdx.x;
    int C = (N + 1023) / 1024;
    int beg = t * C, end = beg + C; if (end > N) end = N; if (beg > N) beg = N;
    int s = 0;
    for (int i = beg; i < end; ++i) s += cnt[i];
    sums[t] = s;
    __syncthreads();
    for (int d = 1; d < 1024; d <<= 1) {
        int v = (t >= d) ? sums[t - d] : 0;
        __syncthreads();
        sums[t] += v;
        __syncthreads();
    }
    int pre = (t == 0) ? 0 : sums[t - 1];
    for (int i = beg; i < end; ++i) { rowptr[i] = pre; pre += cnt[i]; }
    if (t == 1023) rowptr[N] = pre;
}
__global__ void k_fill(const int* __restrict__ row, const int* __restrict__ col,
                       const int* __restrict__ rowptr, const int* __restrict__ pos,
                       int* __restrict__ erow, int E) {
    int e = blockIdx.x * blockDim.x + threadIdx.x;
    if (e < E) erow[rowptr[col[e]] + pos[e]] = row[e];
}

// ---- x f32 -> xb bf16 (vectorized) ----
__global__ void k_xconv(const float4* __restrict__ x, ushort4* __restrict__ xb, int n4) {
    int i = blockIdx.x * blockDim.x + threadIdx.x;
    if (i < n4) {
        float4 v = x[i];
        ushort4 o;
        o.x = f2bf(v.x); o.y = f2bf(v.y); o.z = f2bf(v.z); o.w = f2bf(v.w);
        xb[i] = o;
    }
}

// ---- W_in -> B-fragment-packed bf16: Wb[(c*4+ks)*64 + lane][j] ----
// B layout for mfma_f32_16x16x32_bf16: col = lane&15, k = (lane>>4)*8 + j
__global__ void k_wprep(const float* __restrict__ W, unsigned short* __restrict__ Wb) {
    int tid = blockIdx.x * 256 + threadIdx.x;          // 2048 threads total
    int c = tid >> 8, ks = (tid >> 6) & 3, l = tid & 63;
    int colw  = c * 16 + (l & 15);
    int kbase = ks * 32 + (l >> 4) * 8;
    unsigned short tmp[8];
    #pragma unroll
    for (int j = 0; j < 8; ++j) tmp[j] = f2bf(W[(kbase + j) * HD + colw]);
    #pragma unroll
    for (int j = 0; j < 8; ++j) Wb[tid * 8 + j] = tmp[j];
}

// ---- h0 = relu(x @ W_in + b_in) via MFMA; writes f32 h0 + bf16 hb ----
// wave computes 16 rows x 128 cols; A: row=lane&15, k=(lane>>4)*8+j;
// D: col=lane&15, row=(lane>>4)*4+reg  [m89-verified mapping]
__global__ __launch_bounds__(256) void k_gemm_mfma(
        const unsigned short* __restrict__ xb, const unsigned short* __restrict__ Wb,
        const float* __restrict__ bias,
        float* __restrict__ h0, unsigned short* __restrict__ hb, int N) {
    int wid  = blockIdx.x * 4 + (threadIdx.x >> 6);
    int lane = threadIdx.x & 63;
    int r0 = wid * 16;
    int lr = lane & 15, lg = lane >> 4;
    f32x4 acc[8];
    #pragma unroll
    for (int c = 0; c < 8; ++c) acc[c] = (f32x4){0.f, 0.f, 0.f, 0.f};
    #pragma unroll
    for (int ks = 0; ks < 4; ++ks) {
        short8v a = *(const short8v*)(xb + (size_t)(r0 + lr) * HD + ks * 32 + lg * 8);
        #pragma unroll
        for (int c = 0; c < 8; ++c) {
            short8v b = *(const short8v*)(Wb + ((c * 4 + ks) * 64 + lane) * 8);
            acc[c] = __builtin_amdgcn_mfma_f32_16x16x32_bf16(a, b, acc[c], 0, 0, 0);
        }
    }
    #pragma unroll
    for (int c = 0; c < 8; ++c) {
        int col = c * 16 + lr;
        float bv = bias[col];
        #pragma unroll
        for (int i = 0; i < 4; ++i) {
            int r = r0 + lg * 4 + i;
            if (r < N) {
                float v = acc[c][i] + bv;
                v = v > 0.0f ? v : 0.0f;
                h0[(size_t)r * HD + col] = v;
                hb[(size_t)r * HD + col] = f2bf(v);
            }
        }
    }
}

// ---- layer-0 gate projections from bf16 h ----
__global__ __launch_bounds__(256) void k_ab(
        const unsigned short* __restrict__ hb, const float* __restrict__ Wg,
        const float* __restrict__ bg, int layer, const float* __restrict__ dn,
        float2* __restrict__ adn, float* __restrict__ bplus, int N) {
    int wid  = (int)((blockIdx.x * (size_t)blockDim.x + threadIdx.x) >> 6);
    int lane = threadIdx.x & 63;
    if (wid >= N) return;
    unsigned u = *(const unsigned*)(hb + (size_t)wid * HD + lane * 2);
    float h0v = bf2f(u & 0xffffu), h1v = bf2f(u >> 16);
    float2 w1 = *(const float2*)(Wg + lane * 2);
    float2 w2 = *(const float2*)(Wg + HD + lane * 2);
    float pa = h0v * w1.x + h1v * w1.y;
    float pb = h0v * w2.x + h1v * w2.y;
    #pragma unroll
    for (int m = 32; m; m >>= 1) {
        pa += __shfl_xor(pa, m);
        pb += __shfl_xor(pb, m);
    }
    if (lane == 0) {
        adn[wid]   = make_float2(pa, dn[wid]);
        bplus[wid] = pb + bg[layer];
    }
}

// ---- aggregate + residual + (fused) next-layer gate projections ----
// h_out[v] = EPS*h0[v] + dn[v] * sum_e tanh(a[r]+bplus[v]) * dn[r] * h_in[r]
__global__ __launch_bounds__(256) void k_agg(
        const int* __restrict__ rowptr, const int* __restrict__ erow,
        const float2* __restrict__ adn, const float* __restrict__ bplus,
        const float* __restrict__ dn,
        const unsigned short* __restrict__ hb_in, const float* __restrict__ h0,
        unsigned short* __restrict__ hb_out,
        const float* __restrict__ wg_next, const float* __restrict__ bg, int next_layer,
        float2* __restrict__ adn_out, float* __restrict__ bplus_out, int N) {
    int v = (int)((blockIdx.x * (size_t)blockDim.x + threadIdx.x) >> 6);
    if (v >= N) return;
    int lane = threadIdx.x & 63;
    int beg = rowptr[v], end = rowptr[v + 1];
    float bv = bplus[v];
    float accx = 0.0f, accy = 0.0f;
    for (int s0 = beg; s0 < end; s0 += 64) {
        int m = end - s0; if (m > 64) m = 64;
        int r_l = 0; float nrm_l = 0.0f;
        if (lane < m) {
            r_l = erow[s0 + lane];
            float2 ad = adn[r_l];
            nrm_l = tanhf(ad.x + bv) * ad.y;     // dn[v] factored out of the sum
        }
        for (int j = 0; j < m; ++j) {
            int   r  = __shfl(r_l, j);
            float nv = __shfl(nrm_l, j);
            unsigned u = *(const unsigned*)(hb_in + (size_t)r * HD + lane * 2);
            accx += nv * bf2f(u & 0xffffu);
            accy += nv * bf2f(u >> 16);
        }
    }
    float dnv = dn[v];
    float2 rw = *(const float2*)(h0 + (size_t)v * HD + lane * 2);
    float ox = EPS_RES * rw.x + dnv * accx;
    float oy = EPS_RES * rw.y + dnv * accy;
    unsigned up = (unsigned)f2bf(ox) | ((unsigned)f2bf(oy) << 16);
    *(unsigned*)(hb_out + (size_t)v * HD + lane * 2) = up;
    if (wg_next != nullptr) {
        float2 w1 = *(const float2*)(wg_next + lane * 2);
        float2 w2 = *(const float2*)(wg_next + HD + lane * 2);
        float pa = ox * w1.x + oy * w1.y;
        float pb = ox * w2.x + oy * w2.y;
        #pragma unroll
        for (int m = 32; m; m >>= 1) {
            pa += __shfl_xor(pa, m);
            pb += __shfl_xor(pb, m);
        }
        if (lane == 0) {
            adn_out[v]   = make_float2(pa, dnv);
            bplus_out[v] = pb + bg[next_layer];
        }
    }
}

// ---- out = log_softmax(h @ W_out + b_out); 16 threads/node, bf16 h ----
__global__ __launch_bounds__(256) void k_out(
        const unsigned short* __restrict__ hb, const float* __restrict__ W,
        const float* __restrict__ bias, float* __restrict__ out, int N) {
    __shared__ float Ws[HD * OD];       // 8 KB
    __shared__ unsigned hsu[16 * 64];   // 4 KB: 16 nodes x 64 bf16-pairs
    int t = threadIdx.x;
    for (int i = t; i < HD * OD; i += 256) Ws[i] = W[i];
    int n0 = blockIdx.x * 16;
    for (int i = t; i < 16 * 64; i += 256) {
        int node = n0 + (i >> 6);
        hsu[i] = (node < N) ? *(const unsigned*)(hb + (size_t)node * HD + (i & 63) * 2) : 0u;
    }
    __syncthreads();
    int n = n0 + (t >> 4);
    int j = t & 15;
    if (n < N) {
        const unsigned* hrow = &hsu[(t >> 4) * 64];
        float acc = bias[j];
        #pragma unroll 8
        for (int p = 0; p < 64; ++p) {
            unsigned u = hrow[p];
            acc += bf2f(u & 0xffffu) * Ws[(2 * p) * OD + j]
                 + bf2f(u >> 16)     * Ws[(2 * p + 1) * OD + j];
        }
        float m = acc;
        #pragma unroll
        for (int msk = 8; msk; msk >>= 1) m = fmaxf(m, __shfl_xor(m, msk, 16));
        float ex = expf(acc - m);
        float s = ex;
        #pragma unroll
        for (int msk = 8; msk; msk >>= 1) s += __shfl_xor(s, msk, 16);
        out[n * OD + j] = acc - m - logf(s);
    }
}

extern "C" void kernel_launch(void* const* d_in, const int* in_sizes, int n_in,
                              void* d_out, int out_size, void* d_ws, size_t ws_size,
                              hipStream_t stream) {
    const float* x     = (const float*)d_in[0];
    const int*   ei    = (const int*)  d_in[1];
    const float* W_in  = (const float*)d_in[2];
    const float* b_in  = (const float*)d_in[3];
    const float* Wg    = (const float*)d_in[4];
    const float* bg    = (const float*)d_in[5];
    const float* W_out = (const float*)d_in[6];
    const float* b_out = (const float*)d_in[7];
    float* out = (float*)d_out;

    const int N = in_sizes[0] / HD;
    const int E = in_sizes[1] / 2;
    const int L = in_sizes[5];
    const int* row = ei;
    const int* col = ei + E;

    const int tiles   = (N + 15) / 16;
    const int gblocks = (tiles + 3) / 4;
    const int Npad    = gblocks * 64;       // xb row padding for unguarded A loads

    // ---- workspace bump allocator (256B aligned) ----
    char* ws = (char*)d_ws;
    size_t off = 0;
    auto alloc = [&](size_t bytes) -> void* {
        void* p = ws + off;
        off = (off + bytes + 255) & ~(size_t)255;
        return p;
    };
    float*          dn     = (float*)         alloc((size_t)N * 4);
    float2*         adnA   = (float2*)        alloc((size_t)N * 8);
    float2*         adnB   = (float2*)        alloc((size_t)N * 8);
    float*          bplusA = (float*)         alloc((size_t)N * 4);
    float*          bplusB = (float*)         alloc((size_t)N * 4);
    int*            cnt    = (int*)           alloc((size_t)N * 4);
    int*            rowptr = (int*)           alloc(((size_t)N + 1) * 4);
    int*            pos    = (int*)           alloc((size_t)E * 4);
    int*            erow   = (int*)           alloc((size_t)E * 4);
    unsigned short* xb     = (unsigned short*)alloc((size_t)Npad * HD * 2);
    unsigned short* Wb     = (unsigned short*)alloc((size_t)HD * HD * 2);
    float*          h0     = (float*)         alloc((size_t)N * HD * 4);
    unsigned short* hb0    = (unsigned short*)alloc((size_t)N * HD * 2);
    unsigned short* hb1    = (unsigned short*)alloc((size_t)N * HD * 2);
    unsigned short* hb2    = (unsigned short*)alloc((size_t)N * HD * 2);
    (void)ws_size;

    // degree -> dn
    hipMemsetAsync(dn, 0, (size_t)N * 4, stream);
    k_deg<<<(E + 255) / 256, 256, 0, stream>>>(row, dn, E);
    k_dn <<<(N + 255) / 256, 256, 0, stream>>>(dn, N);

    // CSR by destination
    hipMemsetAsync(cnt, 0, (size_t)N * 4, stream);
    k_count<<<(E + 255) / 256, 256, 0, stream>>>(col, cnt, pos, E);
    k_scan <<<1, 1024, 0, stream>>>(cnt, rowptr, N);
    k_fill <<<(E + 255) / 256, 256, 0, stream>>>(row, col, rowptr, pos, erow, E);

    // bf16 conversion + weight prep + MFMA GEMM
    int n4 = N * HD / 4;
    k_xconv<<<(n4 + 255) / 256, 256, 0, stream>>>((const float4*)x, (ushort4*)xb, n4);
    k_wprep<<<8, 256, 0, stream>>>(W_in, Wb);
    k_gemm_mfma<<<gblocks, 256, 0, stream>>>(xb, Wb, b_in, h0, hb0, N);

    // layer 0 gate projections
    k_ab<<<(N + 3) / 4, 256, 0, stream>>>(hb0, Wg, bg, 0, dn, adnA, bplusA, N);

    unsigned short* hcur = hb0;
    unsigned short* houts[2] = { hb1, hb2 };
    float2* adns[2]  = { adnA, adnB };
    float*  bpls[2]  = { bplusA, bplusB };
    for (int i = 0; i < L; ++i) {
        const float* wg_next = (i + 1 < L) ? (Wg + (i + 1) * 2 * HD) : nullptr;
        k_agg<<<(N + 3) / 4, 256, 0, stream>>>(
            rowptr, erow, adns[i & 1], bpls[i & 1], dn,
            hcur, h0, houts[i & 1],
            wg_next, bg, i + 1, adns[(i + 1) & 1], bpls[(i + 1) & 1], N);
        hcur = houts[i & 1];
    }

    k_out<<<(N + 15) / 16, 256, 0, stream>>>(hcur, W_out, b_out, out, N);
}

// Round 5
// 332.837 us; speedup vs baseline: 4.8508x; 1.2796x over previous
//
#include <hip/hip_runtime.h>
#include <hip/hip_bf16.h>
#include <math.h>

// FAGCN: N=50000, E=800000, H=128, OUT=16, L=2
// Round 4 -> 5: (1) single-block k_scan (78us, 0.15% occ) -> 3-phase hierarchical
// scan; (2) fuse deg+count histograms into one edge pass; (3) GEMM reads f32 x
// directly (kills k_xconv, -64MB traffic); (4) layer-0 gate projections fused
// into GEMM epilogue (kills k_ab).

#define EPS_RES 0.3f
constexpr int HD = 128;
constexpr int OD = 16;

typedef __attribute__((ext_vector_type(8))) short short8v;   // 8 x bf16 (4 VGPR)
typedef __attribute__((ext_vector_type(4))) float f32x4;

__device__ __forceinline__ unsigned short f2bf(float f) {    // RNE f32->bf16
    unsigned u = __builtin_bit_cast(unsigned, f);
    u += 0x7fffu + ((u >> 16) & 1u);
    return (unsigned short)(u >> 16);
}
__device__ __forceinline__ float bf2f(unsigned s) {
    return __builtin_bit_cast(float, s << 16);
}

// ---- fused edge histograms: deg by row (for dn), cnt+pos by col (for CSR) ----
__global__ void k_edge(const int* __restrict__ row, const int* __restrict__ col,
                       int* __restrict__ degi, int* __restrict__ cnt,
                       int* __restrict__ pos, int E) {
    int e = blockIdx.x * blockDim.x + threadIdx.x;
    if (e < E) {
        atomicAdd(&degi[row[e]], 1);
        pos[e] = atomicAdd(&cnt[col[e]], 1);
    }
}

__global__ void k_dn(const int* __restrict__ degi, float* __restrict__ dn, int N) {
    int v = blockIdx.x * blockDim.x + threadIdx.x;
    if (v < N) {
        int d = degi[v];
        d = d < 1 ? 1 : d;
        dn[v] = rsqrtf((float)d);
    }
}

// ---- hierarchical exclusive scan of cnt[N] -> rowptr[N+1] ----
__global__ __launch_bounds__(256) void k_scan1(const int* __restrict__ cnt,
                                               int* __restrict__ bsum, int N) {
    __shared__ int s[256];
    int t = threadIdx.x, i = blockIdx.x * 256 + t;
    s[t] = (i < N) ? cnt[i] : 0;
    __syncthreads();
    #pragma unroll
    for (int d = 128; d; d >>= 1) {
        if (t < d) s[t] += s[t + d];
        __syncthreads();
    }
    if (t == 0) bsum[blockIdx.x] = s[0];
}

__global__ __launch_bounds__(256) void k_scan2(int* __restrict__ bsum, int nb,
                                               int* __restrict__ rowptr, int N, int E) {
    __shared__ int s[256];
    int t = threadIdx.x;
    int v = (t < nb) ? bsum[t] : 0;
    s[t] = v;
    __syncthreads();
    #pragma unroll
    for (int d = 1; d < 256; d <<= 1) {
        int x = (t >= d) ? s[t - d] : 0;
        __syncthreads();
        s[t] += x;
        __syncthreads();
    }
    if (t < nb) bsum[t] = s[t] - v;   // exclusive block offsets
    if (t == 0) rowptr[N] = E;
}

__global__ __launch_bounds__(256) void k_scan3(const int* __restrict__ cnt,
                                               const int* __restrict__ bsum,
                                               int* __restrict__ rowptr, int N) {
    __shared__ int s[256];
    int t = threadIdx.x, i = blockIdx.x * 256 + t;
    int v = (i < N) ? cnt[i] : 0;
    s[t] = v;
    __syncthreads();
    #pragma unroll
    for (int d = 1; d < 256; d <<= 1) {
        int x = (t >= d) ? s[t - d] : 0;
        __syncthreads();
        s[t] += x;
        __syncthreads();
    }
    if (i < N) rowptr[i] = bsum[blockIdx.x] + s[t] - v;
}

__global__ void k_fill(const int* __restrict__ row, const int* __restrict__ col,
                       const int* __restrict__ rowptr, const int* __restrict__ pos,
                       int* __restrict__ erow, int E) {
    int e = blockIdx.x * blockDim.x + threadIdx.x;
    if (e < E) erow[rowptr[col[e]] + pos[e]] = row[e];
}

// ---- W_in -> B-fragment-packed bf16 ----
__global__ void k_wprep(const float* __restrict__ W, unsigned short* __restrict__ Wb) {
    int tid = blockIdx.x * 256 + threadIdx.x;          // 2048 threads
    int c = tid >> 8, ks = (tid >> 6) & 3, l = tid & 63;
    int colw  = c * 16 + (l & 15);
    int kbase = ks * 32 + (l >> 4) * 8;
    unsigned short tmp[8];
    #pragma unroll
    for (int j = 0; j < 8; ++j) tmp[j] = f2bf(W[(kbase + j) * HD + colw]);
    #pragma unroll
    for (int j = 0; j < 8; ++j) Wb[tid * 8 + j] = tmp[j];
}

// ---- h0 = relu(x @ W_in + b_in) via MFMA, reading f32 x directly.
// Also writes bf16 hb and fused layer-0 gate projections (adn, bplus).
__global__ __launch_bounds__(256) void k_gemm_mfma(
        const float* __restrict__ x, const unsigned short* __restrict__ Wb,
        const float* __restrict__ bias,
        const float* __restrict__ Wg0, const float* __restrict__ bg,
        const float* __restrict__ dn,
        float* __restrict__ h0, unsigned short* __restrict__ hb,
        float2* __restrict__ adn, float* __restrict__ bplus, int N) {
    int wid  = blockIdx.x * 4 + (threadIdx.x >> 6);
    int lane = threadIdx.x & 63;
    int r0 = wid * 16;
    int lr = lane & 15, lg = lane >> 4;
    int rload = r0 + lr; if (rload > N - 1) rload = N - 1;   // clamp tail loads
    f32x4 acc[8];
    #pragma unroll
    for (int c = 0; c < 8; ++c) acc[c] = (f32x4){0.f, 0.f, 0.f, 0.f};
    #pragma unroll
    for (int ks = 0; ks < 4; ++ks) {
        const float4* xr = (const float4*)(x + (size_t)rload * HD + ks * 32 + lg * 8);
        float4 f0 = xr[0], f1 = xr[1];
        short8v a;
        a[0] = (short)f2bf(f0.x); a[1] = (short)f2bf(f0.y);
        a[2] = (short)f2bf(f0.z); a[3] = (short)f2bf(f0.w);
        a[4] = (short)f2bf(f1.x); a[5] = (short)f2bf(f1.y);
        a[6] = (short)f2bf(f1.z); a[7] = (short)f2bf(f1.w);
        #pragma unroll
        for (int c = 0; c < 8; ++c) {
            short8v b = *(const short8v*)(Wb + ((c * 4 + ks) * 64 + lane) * 8);
            acc[c] = __builtin_amdgcn_mfma_f32_16x16x32_bf16(a, b, acc[c], 0, 0, 0);
        }
    }
    float pa[4] = {0.f, 0.f, 0.f, 0.f}, pb[4] = {0.f, 0.f, 0.f, 0.f};
    #pragma unroll
    for (int c = 0; c < 8; ++c) {
        int colw = c * 16 + lr;
        float bv = bias[colw];
        float w1 = Wg0[colw], w2 = Wg0[HD + colw];
        #pragma unroll
        for (int i = 0; i < 4; ++i) {
            int r = r0 + lg * 4 + i;
            float v = acc[c][i] + bv;
            v = v > 0.0f ? v : 0.0f;
            if (r < N) {
                h0[(size_t)r * HD + colw] = v;
                hb[(size_t)r * HD + colw] = f2bf(v);
            }
            pa[i] += v * w1;
            pb[i] += v * w2;
        }
    }
    #pragma unroll
    for (int mask = 1; mask <= 8; mask <<= 1) {
        #pragma unroll
        for (int i = 0; i < 4; ++i) {
            pa[i] += __shfl_xor(pa[i], mask);
            pb[i] += __shfl_xor(pb[i], mask);
        }
    }
    if (lr == 0) {
        float bg0 = bg[0];
        #pragma unroll
        for (int i = 0; i < 4; ++i) {
            int r = r0 + lg * 4 + i;
            if (r < N) {
                adn[r]   = make_float2(pa[i], dn[r]);
                bplus[r] = pb[i] + bg0;
            }
        }
    }
}

// ---- aggregate + residual + (fused) next-layer gate projections ----
__global__ __launch_bounds__(256) void k_agg(
        const int* __restrict__ rowptr, const int* __restrict__ erow,
        const float2* __restrict__ adn, const float* __restrict__ bplus,
        const float* __restrict__ dn,
        const unsigned short* __restrict__ hb_in, const float* __restrict__ h0,
        unsigned short* __restrict__ hb_out,
        const float* __restrict__ wg_next, const float* __restrict__ bg, int next_layer,
        float2* __restrict__ adn_out, float* __restrict__ bplus_out, int N) {
    int v = (int)((blockIdx.x * (size_t)blockDim.x + threadIdx.x) >> 6);
    if (v >= N) return;
    int lane = threadIdx.x & 63;
    int beg = rowptr[v], end = rowptr[v + 1];
    float bv = bplus[v];
    float accx = 0.0f, accy = 0.0f;
    for (int s0 = beg; s0 < end; s0 += 64) {
        int m = end - s0; if (m > 64) m = 64;
        int r_l = 0; float nrm_l = 0.0f;
        if (lane < m) {
            r_l = erow[s0 + lane];
            float2 ad = adn[r_l];
            nrm_l = tanhf(ad.x + bv) * ad.y;     // dn[v] factored out
        }
        for (int j = 0; j < m; ++j) {
            int   r  = __shfl(r_l, j);
            float nv = __shfl(nrm_l, j);
            unsigned u = *(const unsigned*)(hb_in + (size_t)r * HD + lane * 2);
            accx += nv * bf2f(u & 0xffffu);
            accy += nv * bf2f(u >> 16);
        }
    }
    float dnv = dn[v];
    float2 rw = *(const float2*)(h0 + (size_t)v * HD + lane * 2);
    float ox = EPS_RES * rw.x + dnv * accx;
    float oy = EPS_RES * rw.y + dnv * accy;
    unsigned up = (unsigned)f2bf(ox) | ((unsigned)f2bf(oy) << 16);
    *(unsigned*)(hb_out + (size_t)v * HD + lane * 2) = up;
    if (wg_next != nullptr) {
        float2 w1 = *(const float2*)(wg_next + lane * 2);
        float2 w2 = *(const float2*)(wg_next + HD + lane * 2);
        float pa = ox * w1.x + oy * w1.y;
        float pb = ox * w2.x + oy * w2.y;
        #pragma unroll
        for (int m = 32; m; m >>= 1) {
            pa += __shfl_xor(pa, m);
            pb += __shfl_xor(pb, m);
        }
        if (lane == 0) {
            adn_out[v]   = make_float2(pa, dnv);
            bplus_out[v] = pb + bg[next_layer];
        }
    }
}

// ---- out = log_softmax(h @ W_out + b_out); 16 threads/node, bf16 h ----
__global__ __launch_bounds__(256) void k_out(
        const unsigned short* __restrict__ hb, const float* __restrict__ W,
        const float* __restrict__ bias, float* __restrict__ out, int N) {
    __shared__ float Ws[HD * OD];
    __shared__ unsigned hsu[16 * 64];
    int t = threadIdx.x;
    for (int i = t; i < HD * OD; i += 256) Ws[i] = W[i];
    int n0 = blockIdx.x * 16;
    for (int i = t; i < 16 * 64; i += 256) {
        int node = n0 + (i >> 6);
        hsu[i] = (node < N) ? *(const unsigned*)(hb + (size_t)node * HD + (i & 63) * 2) : 0u;
    }
    __syncthreads();
    int n = n0 + (t >> 4);
    int j = t & 15;
    if (n < N) {
        const unsigned* hrow = &hsu[(t >> 4) * 64];
        float acc = bias[j];
        #pragma unroll 8
        for (int p = 0; p < 64; ++p) {
            unsigned u = hrow[p];
            acc += bf2f(u & 0xffffu) * Ws[(2 * p) * OD + j]
                 + bf2f(u >> 16)     * Ws[(2 * p + 1) * OD + j];
        }
        float m = acc;
        #pragma unroll
        for (int msk = 8; msk; msk >>= 1) m = fmaxf(m, __shfl_xor(m, msk, 16));
        float ex = expf(acc - m);
        float s = ex;
        #pragma unroll
        for (int msk = 8; msk; msk >>= 1) s += __shfl_xor(s, msk, 16);
        out[n * OD + j] = acc - m - logf(s);
    }
}

extern "C" void kernel_launch(void* const* d_in, const int* in_sizes, int n_in,
                              void* d_out, int out_size, void* d_ws, size_t ws_size,
                              hipStream_t stream) {
    const float* x     = (const float*)d_in[0];
    const int*   ei    = (const int*)  d_in[1];
    const float* W_in  = (const float*)d_in[2];
    const float* b_in  = (const float*)d_in[3];
    const float* Wg    = (const float*)d_in[4];
    const float* bg    = (const float*)d_in[5];
    const float* W_out = (const float*)d_in[6];
    const float* b_out = (const float*)d_in[7];
    float* out = (float*)d_out;

    const int N = in_sizes[0] / HD;
    const int E = in_sizes[1] / 2;
    const int L = in_sizes[5];
    const int* row = ei;
    const int* col = ei + E;

    const int tiles   = (N + 15) / 16;
    const int gblocks = (tiles + 3) / 4;
    const int nb      = (N + 255) / 256;    // scan blocks (196 <= 256)

    // ---- workspace bump allocator (256B aligned) ----
    char* ws = (char*)d_ws;
    size_t off = 0;
    auto alloc = [&](size_t bytes) -> void* {
        void* p = ws + off;
        off = (off + bytes + 255) & ~(size_t)255;
        return p;
    };
    int*            degi   = (int*)           alloc((size_t)N * 4);   // adjacent with cnt:
    int*            cnt    = (int*)           alloc((size_t)N * 4);   // single memset
    float*          dn     = (float*)         alloc((size_t)N * 4);
    float2*         adnA   = (float2*)        alloc((size_t)N * 8);
    float2*         adnB   = (float2*)        alloc((size_t)N * 8);
    float*          bplusA = (float*)         alloc((size_t)N * 4);
    float*          bplusB = (float*)         alloc((size_t)N * 4);
    int*            bsum   = (int*)           alloc((size_t)nb * 4);
    int*            rowptr = (int*)           alloc(((size_t)N + 1) * 4);
    int*            pos    = (int*)           alloc((size_t)E * 4);
    int*            erow   = (int*)           alloc((size_t)E * 4);
    unsigned short* Wb     = (unsigned short*)alloc((size_t)HD * HD * 2);
    float*          h0     = (float*)         alloc((size_t)N * HD * 4);
    unsigned short* hb0    = (unsigned short*)alloc((size_t)N * HD * 2);
    unsigned short* hb1    = (unsigned short*)alloc((size_t)N * HD * 2);
    unsigned short* hb2    = (unsigned short*)alloc((size_t)N * HD * 2);
    (void)ws_size;

    // zero degi+cnt in one memset (adjacent allocations)
    hipMemsetAsync(degi, 0, (size_t)((char*)cnt - (char*)degi) + (size_t)N * 4, stream);

    // fused histograms
    k_edge<<<(E + 255) / 256, 256, 0, stream>>>(row, col, degi, cnt, pos, E);
    k_dn  <<<(N + 255) / 256, 256, 0, stream>>>(degi, dn, N);

    // hierarchical scan -> rowptr, then fill
    k_scan1<<<nb, 256, 0, stream>>>(cnt, bsum, N);
    k_scan2<<<1, 256, 0, stream>>>(bsum, nb, rowptr, N, E);
    k_scan3<<<nb, 256, 0, stream>>>(cnt, bsum, rowptr, N);
    k_fill <<<(E + 255) / 256, 256, 0, stream>>>(row, col, rowptr, pos, erow, E);

    // weight prep + MFMA GEMM (reads f32 x, fused layer-0 gate projections)
    k_wprep<<<8, 256, 0, stream>>>(W_in, Wb);
    k_gemm_mfma<<<gblocks, 256, 0, stream>>>(x, Wb, b_in, Wg, bg, dn,
                                             h0, hb0, adnA, bplusA, N);

    unsigned short* hcur = hb0;
    unsigned short* houts[2] = { hb1, hb2 };
    float2* adns[2]  = { adnA, adnB };
    float*  bpls[2]  = { bplusA, bplusB };
    for (int i = 0; i < L; ++i) {
        const float* wg_next = (i + 1 < L) ? (Wg + (i + 1) * 2 * HD) : nullptr;
        k_agg<<<(N + 3) / 4, 256, 0, stream>>>(
            rowptr, erow, adns[i & 1], bpls[i & 1], dn,
            hcur, h0, houts[i & 1],
            wg_next, bg, i + 1, adns[(i + 1) & 1], bpls[(i + 1) & 1], N);
        hcur = houts[i & 1];
    }

    k_out<<<(N + 15) / 16, 256, 0, stream>>>(hcur, W_out, b_out, out, N);
}

// Round 6
// 297.799 us; speedup vs baseline: 5.4215x; 1.1177x over previous
//
#include <hip/hip_runtime.h>
#include <hip/hip_bf16.h>
#include <math.h>

// FAGCN: N=50000, E=800000, H=128, OUT=16, L=2
// Round 5 -> 6: (1) k_edge contention fix: 8-way sub-histograms (line-level
// atomic serialization was 80us); (2) k_agg half-wave 2-edges/iter (halves
// shfl chain, 8B gathers); (3) f32 h0 dropped, residual from bf16 hb0
// (-45MB traffic); (4) k_dn/reduction/scan1 merged into k_red.

#define EPS_RES 0.3f
constexpr int HD = 128;
constexpr int OD = 16;
constexpr int NSUB = 8;

typedef __attribute__((ext_vector_type(8))) short short8v;   // 8 x bf16
typedef __attribute__((ext_vector_type(4))) float f32x4;

__device__ __forceinline__ unsigned short f2bf(float f) {    // RNE f32->bf16
    unsigned u = __builtin_bit_cast(unsigned, f);
    u += 0x7fffu + ((u >> 16) & 1u);
    return (unsigned short)(u >> 16);
}
__device__ __forceinline__ float bf2f(unsigned s) {
    return __builtin_bit_cast(float, s << 16);
}

// ---- edge histograms into 8 sub-copies (contention /8) ----
__global__ void k_edge(const int* __restrict__ row, const int* __restrict__ col,
                       int* __restrict__ degi8, int* __restrict__ cnt8,
                       int* __restrict__ pos, int E, int N) {
    int e = blockIdx.x * blockDim.x + threadIdx.x;
    if (e < E) {
        int s = blockIdx.x & (NSUB - 1);
        atomicAdd(&degi8[s * N + row[e]], 1);
        pos[e] = atomicAdd(&cnt8[s * N + col[e]], 1);
    }
}

// ---- reduce sub-histograms: dn, in-place exclusive sub-prefix, cnt, scan1 partials ----
__global__ __launch_bounds__(256) void k_red(int* __restrict__ degi8, int* __restrict__ cnt8,
                                             float* __restrict__ dn, int* __restrict__ cnt,
                                             int* __restrict__ bsum, int N) {
    int t = threadIdx.x, i = blockIdx.x * 256 + t;
    int total = 0;
    if (i < N) {
        int deg = 0;
        #pragma unroll
        for (int s = 0; s < NSUB; ++s) deg += degi8[s * N + i];
        dn[i] = rsqrtf((float)(deg < 1 ? 1 : deg));
        int run = 0;
        #pragma unroll
        for (int s = 0; s < NSUB; ++s) {
            int c = cnt8[s * N + i];
            cnt8[s * N + i] = run;          // exclusive prefix across subs
            run += c;
        }
        total = run;
        cnt[i] = total;
    }
    __shared__ int sh[256];
    sh[t] = total;
    __syncthreads();
    #pragma unroll
    for (int d = 128; d; d >>= 1) {
        if (t < d) sh[t] += sh[t + d];
        __syncthreads();
    }
    if (t == 0) bsum[blockIdx.x] = sh[0];
}

__global__ __launch_bounds__(256) void k_scan2(int* __restrict__ bsum, int nb,
                                               int* __restrict__ rowptr, int N, int E) {
    __shared__ int s[256];
    int t = threadIdx.x;
    int v = (t < nb) ? bsum[t] : 0;
    s[t] = v;
    __syncthreads();
    #pragma unroll
    for (int d = 1; d < 256; d <<= 1) {
        int x = (t >= d) ? s[t - d] : 0;
        __syncthreads();
        s[t] += x;
        __syncthreads();
    }
    if (t < nb) bsum[t] = s[t] - v;
    if (t == 0) rowptr[N] = E;
}

// rowptr[i] = global offset; also bake rowptr into the 8 sub-bases in place
__global__ __launch_bounds__(256) void k_scan3(const int* __restrict__ cnt,
                                               const int* __restrict__ bsum,
                                               int* __restrict__ rowptr,
                                               int* __restrict__ cnt8, int N) {
    __shared__ int s[256];
    int t = threadIdx.x, i = blockIdx.x * 256 + t;
    int v = (i < N) ? cnt[i] : 0;
    s[t] = v;
    __syncthreads();
    #pragma unroll
    for (int d = 1; d < 256; d <<= 1) {
        int x = (t >= d) ? s[t - d] : 0;
        __syncthreads();
        s[t] += x;
        __syncthreads();
    }
    if (i < N) {
        int rp = bsum[blockIdx.x] + s[t] - v;
        rowptr[i] = rp;
        #pragma unroll
        for (int ss = 0; ss < NSUB; ++ss) cnt8[ss * N + i] += rp;
    }
}

// same e->s mapping as k_edge (same grid shape)
__global__ void k_fill(const int* __restrict__ row, const int* __restrict__ col,
                       const int* __restrict__ cnt8, const int* __restrict__ pos,
                       int* __restrict__ erow, int E, int N) {
    int e = blockIdx.x * blockDim.x + threadIdx.x;
    if (e < E) {
        int s = blockIdx.x & (NSUB - 1);
        erow[cnt8[s * N + col[e]] + pos[e]] = row[e];
    }
}

// ---- W_in -> B-fragment-packed bf16 ----
__global__ void k_wprep(const float* __restrict__ W, unsigned short* __restrict__ Wb) {
    int tid = blockIdx.x * 256 + threadIdx.x;          // 2048 threads
    int c = tid >> 8, ks = (tid >> 6) & 3, l = tid & 63;
    int colw  = c * 16 + (l & 15);
    int kbase = ks * 32 + (l >> 4) * 8;
    unsigned short tmp[8];
    #pragma unroll
    for (int j = 0; j < 8; ++j) tmp[j] = f2bf(W[(kbase + j) * HD + colw]);
    #pragma unroll
    for (int j = 0; j < 8; ++j) Wb[tid * 8 + j] = tmp[j];
}

// ---- hb0 = bf16(relu(x @ W_in + b_in)) via MFMA + fused layer-0 gate proj ----
__global__ __launch_bounds__(256) void k_gemm_mfma(
        const float* __restrict__ x, const unsigned short* __restrict__ Wb,
        const float* __restrict__ bias,
        const float* __restrict__ Wg0, const float* __restrict__ bg,
        const float* __restrict__ dn,
        unsigned short* __restrict__ hb,
        float2* __restrict__ adn, float* __restrict__ bplus, int N) {
    int wid  = blockIdx.x * 4 + (threadIdx.x >> 6);
    int lane = threadIdx.x & 63;
    int r0 = wid * 16;
    int lr = lane & 15, lg = lane >> 4;
    int rload = r0 + lr; if (rload > N - 1) rload = N - 1;
    f32x4 acc[8];
    #pragma unroll
    for (int c = 0; c < 8; ++c) acc[c] = (f32x4){0.f, 0.f, 0.f, 0.f};
    #pragma unroll
    for (int ks = 0; ks < 4; ++ks) {
        const float4* xr = (const float4*)(x + (size_t)rload * HD + ks * 32 + lg * 8);
        float4 f0 = xr[0], f1 = xr[1];
        short8v a;
        a[0] = (short)f2bf(f0.x); a[1] = (short)f2bf(f0.y);
        a[2] = (short)f2bf(f0.z); a[3] = (short)f2bf(f0.w);
        a[4] = (short)f2bf(f1.x); a[5] = (short)f2bf(f1.y);
        a[6] = (short)f2bf(f1.z); a[7] = (short)f2bf(f1.w);
        #pragma unroll
        for (int c = 0; c < 8; ++c) {
            short8v b = *(const short8v*)(Wb + ((c * 4 + ks) * 64 + lane) * 8);
            acc[c] = __builtin_amdgcn_mfma_f32_16x16x32_bf16(a, b, acc[c], 0, 0, 0);
        }
    }
    float pa[4] = {0.f, 0.f, 0.f, 0.f}, pb[4] = {0.f, 0.f, 0.f, 0.f};
    #pragma unroll
    for (int c = 0; c < 8; ++c) {
        int colw = c * 16 + lr;
        float bv = bias[colw];
        float w1 = Wg0[colw], w2 = Wg0[HD + colw];
        #pragma unroll
        for (int i = 0; i < 4; ++i) {
            int r = r0 + lg * 4 + i;
            float v = acc[c][i] + bv;
            v = v > 0.0f ? v : 0.0f;
            if (r < N) hb[(size_t)r * HD + colw] = f2bf(v);
            pa[i] += v * w1;
            pb[i] += v * w2;
        }
    }
    #pragma unroll
    for (int mask = 1; mask <= 8; mask <<= 1) {
        #pragma unroll
        for (int i = 0; i < 4; ++i) {
            pa[i] += __shfl_xor(pa[i], mask);
            pb[i] += __shfl_xor(pb[i], mask);
        }
    }
    if (lr == 0) {
        float bg0 = bg[0];
        #pragma unroll
        for (int i = 0; i < 4; ++i) {
            int r = r0 + lg * 4 + i;
            if (r < N) {
                adn[r]   = make_float2(pa[i], dn[r]);
                bplus[r] = pb[i] + bg0;
            }
        }
    }
}

// ---- aggregate + residual(bf16 hb0) + fused next-layer gate projections ----
// half-wave scheme: lanes 0-31 process even edges, 32-63 odd edges;
// lane handles features (lane&31)*4 .. +3 as bf16x4 (8B loads).
__global__ __launch_bounds__(256) void k_agg(
        const int* __restrict__ rowptr, const int* __restrict__ erow,
        const float2* __restrict__ adn, const float* __restrict__ bplus,
        const float* __restrict__ dn,
        const unsigned short* __restrict__ hb_in, const unsigned short* __restrict__ hb0,
        unsigned short* __restrict__ hb_out,
        const float* __restrict__ wg_next, const float* __restrict__ bg, int next_layer,
        float2* __restrict__ adn_out, float* __restrict__ bplus_out, int N) {
    int v = (int)((blockIdx.x * (size_t)blockDim.x + threadIdx.x) >> 6);
    if (v >= N) return;
    int lane = threadIdx.x & 63;
    int hl = lane & 31, half = lane >> 5;
    int beg = rowptr[v], end = rowptr[v + 1];
    float bv = bplus[v];
    float ax = 0.f, ay = 0.f, az = 0.f, aw = 0.f;
    for (int s0 = beg; s0 < end; s0 += 64) {
        int m = end - s0; if (m > 64) m = 64;
        int r_l = 0; float nrm_l = 0.0f;
        if (lane < m) {
            r_l = erow[s0 + lane];
            float2 ad = adn[r_l];
            nrm_l = tanhf(ad.x + bv) * ad.y;     // dn[v] factored out
        }
        int it = (m + 1) >> 1;
        for (int j = 0; j < it; ++j) {
            int src = 2 * j + half;
            int   r  = __shfl(r_l, src);
            float nv = __shfl(nrm_l, src);
            if (src < m) {
                uint2 u = *(const uint2*)(hb_in + (size_t)r * HD + hl * 4);
                ax += nv * bf2f(u.x & 0xffffu);
                ay += nv * bf2f(u.x >> 16);
                az += nv * bf2f(u.y & 0xffffu);
                aw += nv * bf2f(u.y >> 16);
            }
        }
    }
    ax += __shfl_xor(ax, 32);
    ay += __shfl_xor(ay, 32);
    az += __shfl_xor(az, 32);
    aw += __shfl_xor(aw, 32);
    float dnv = dn[v];
    uint2 u0 = *(const uint2*)(hb0 + (size_t)v * HD + hl * 4);
    float o0 = EPS_RES * bf2f(u0.x & 0xffffu) + dnv * ax;
    float o1 = EPS_RES * bf2f(u0.x >> 16)     + dnv * ay;
    float o2 = EPS_RES * bf2f(u0.y & 0xffffu) + dnv * az;
    float o3 = EPS_RES * bf2f(u0.y >> 16)     + dnv * aw;
    if (half == 0) {
        uint2 up;
        up.x = (unsigned)f2bf(o0) | ((unsigned)f2bf(o1) << 16);
        up.y = (unsigned)f2bf(o2) | ((unsigned)f2bf(o3) << 16);
        *(uint2*)(hb_out + (size_t)v * HD + hl * 4) = up;
    }
    if (wg_next != nullptr) {
        float4 w1 = *(const float4*)(wg_next + hl * 4);
        float4 w2 = *(const float4*)(wg_next + HD + hl * 4);
        float pa = o0 * w1.x + o1 * w1.y + o2 * w1.z + o3 * w1.w;
        float pb = o0 * w2.x + o1 * w2.y + o2 * w2.z + o3 * w2.w;
        #pragma unroll
        for (int m = 16; m; m >>= 1) {
            pa += __shfl_xor(pa, m);
            pb += __shfl_xor(pb, m);
        }
        if (lane == 0) {
            adn_out[v]   = make_float2(pa, dnv);
            bplus_out[v] = pb + bg[next_layer];
        }
    }
}

// ---- out = log_softmax(h @ W_out + b_out); 16 threads/node, bf16 h ----
__global__ __launch_bounds__(256) void k_out(
        const unsigned short* __restrict__ hb, const float* __restrict__ W,
        const float* __restrict__ bias, float* __restrict__ out, int N) {
    __shared__ float Ws[HD * OD];
    __shared__ unsigned hsu[16 * 64];
    int t = threadIdx.x;
    for (int i = t; i < HD * OD; i += 256) Ws[i] = W[i];
    int n0 = blockIdx.x * 16;
    for (int i = t; i < 16 * 64; i += 256) {
        int node = n0 + (i >> 6);
        hsu[i] = (node < N) ? *(const unsigned*)(hb + (size_t)node * HD + (i & 63) * 2) : 0u;
    }
    __syncthreads();
    int n = n0 + (t >> 4);
    int j = t & 15;
    if (n < N) {
        const unsigned* hrow = &hsu[(t >> 4) * 64];
        float acc = bias[j];
        #pragma unroll 8
        for (int p = 0; p < 64; ++p) {
            unsigned u = hrow[p];
            acc += bf2f(u & 0xffffu) * Ws[(2 * p) * OD + j]
                 + bf2f(u >> 16)     * Ws[(2 * p + 1) * OD + j];
        }
        float m = acc;
        #pragma unroll
        for (int msk = 8; msk; msk >>= 1) m = fmaxf(m, __shfl_xor(m, msk, 16));
        float ex = expf(acc - m);
        float s = ex;
        #pragma unroll
        for (int msk = 8; msk; msk >>= 1) s += __shfl_xor(s, msk, 16);
        out[n * OD + j] = acc - m - logf(s);
    }
}

extern "C" void kernel_launch(void* const* d_in, const int* in_sizes, int n_in,
                              void* d_out, int out_size, void* d_ws, size_t ws_size,
                              hipStream_t stream) {
    const float* x     = (const float*)d_in[0];
    const int*   ei    = (const int*)  d_in[1];
    const float* W_in  = (const float*)d_in[2];
    const float* b_in  = (const float*)d_in[3];
    const float* Wg    = (const float*)d_in[4];
    const float* bg    = (const float*)d_in[5];
    const float* W_out = (const float*)d_in[6];
    const float* b_out = (const float*)d_in[7];
    float* out = (float*)d_out;

    const int N = in_sizes[0] / HD;
    const int E = in_sizes[1] / 2;
    const int L = in_sizes[5];
    const int* row = ei;
    const int* col = ei + E;

    const int tiles   = (N + 15) / 16;
    const int gblocks = (tiles + 3) / 4;
    const int nb      = (N + 255) / 256;    // 196 <= 256

    // ---- workspace bump allocator (256B aligned) ----
    char* ws = (char*)d_ws;
    size_t off = 0;
    auto alloc = [&](size_t bytes) -> void* {
        void* p = ws + off;
        off = (off + bytes + 255) & ~(size_t)255;
        return p;
    };
    int*            ctr    = (int*)           alloc((size_t)2 * NSUB * N * 4); // degi8|cnt8
    float*          dn     = (float*)         alloc((size_t)N * 4);
    int*            cnt    = (int*)           alloc((size_t)N * 4);
    float2*         adnA   = (float2*)        alloc((size_t)N * 8);
    float2*         adnB   = (float2*)        alloc((size_t)N * 8);
    float*          bplusA = (float*)         alloc((size_t)N * 4);
    float*          bplusB = (float*)         alloc((size_t)N * 4);
    int*            bsum   = (int*)           alloc((size_t)nb * 4);
    int*            rowptr = (int*)           alloc(((size_t)N + 1) * 4);
    int*            pos    = (int*)           alloc((size_t)E * 4);
    int*            erow   = (int*)           alloc((size_t)E * 4);
    unsigned short* Wb     = (unsigned short*)alloc((size_t)HD * HD * 2);
    unsigned short* hb0    = (unsigned short*)alloc((size_t)N * HD * 2);
    unsigned short* hb1    = (unsigned short*)alloc((size_t)N * HD * 2);
    unsigned short* hb2    = (unsigned short*)alloc((size_t)N * HD * 2);
    (void)ws_size;

    int* degi8 = ctr;
    int* cnt8  = ctr + (size_t)NSUB * N;

    hipMemsetAsync(ctr, 0, (size_t)2 * NSUB * N * 4, stream);

    k_edge<<<(E + 255) / 256, 256, 0, stream>>>(row, col, degi8, cnt8, pos, E, N);
    k_red <<<nb, 256, 0, stream>>>(degi8, cnt8, dn, cnt, bsum, N);
    k_scan2<<<1, 256, 0, stream>>>(bsum, nb, rowptr, N, E);
    k_scan3<<<nb, 256, 0, stream>>>(cnt, bsum, rowptr, cnt8, N);
    k_fill <<<(E + 255) / 256, 256, 0, stream>>>(row, col, cnt8, pos, erow, E, N);

    k_wprep<<<8, 256, 0, stream>>>(W_in, Wb);
    k_gemm_mfma<<<gblocks, 256, 0, stream>>>(x, Wb, b_in, Wg, bg, dn,
                                             hb0, adnA, bplusA, N);

    unsigned short* hcur = hb0;
    unsigned short* houts[2] = { hb1, hb2 };
    float2* adns[2]  = { adnA, adnB };
    float*  bpls[2]  = { bplusA, bplusB };
    for (int i = 0; i < L; ++i) {
        const float* wg_next = (i + 1 < L) ? (Wg + (i + 1) * 2 * HD) : nullptr;
        k_agg<<<(N + 3) / 4, 256, 0, stream>>>(
            rowptr, erow, adns[i & 1], bpls[i & 1], dn,
            hcur, hb0, houts[i & 1],
            wg_next, bg, i + 1, adns[(i + 1) & 1], bpls[(i + 1) & 1], N);
        hcur = houts[i & 1];
    }

    k_out<<<(N + 15) / 16, 256, 0, stream>>>(hcur, W_out, b_out, out, N);
}